// Round 4
// baseline (391.296 us; speedup 1.0000x reference)
//
#include <hip/hip_runtime.h>
#include <hip/hip_bf16.h>

typedef __hip_bfloat16 bf16;

// Dims
constexpr int cD0 = 24,  cH0 = 64,  cW0 = 128;   // cv1 / x1 spatial
constexpr int cD1 = 48,  cH1 = 128, cW1 = 256;   // x2 / cv0 / x3 spatial
constexpr int cD2 = 96,  cH2 = 256, cW2 = 512;   // cost / out spatial
constexpr size_t PL0 = (size_t)cD0 * cH0 * cW0;  // 196608
constexpr size_t PL1 = (size_t)cD1 * cH1 * cW1;  // 1572864
constexpr size_t PL2 = (size_t)cD2 * cH2 * cW2;  // 12582912

__device__ __forceinline__ float b2f(bf16 v) { return __bfloat162float(v); }
__device__ __forceinline__ bf16  f2b(float v) { return __float2bfloat16(v); }
__device__ __forceinline__ float lrelu(float v) { return v >= 0.f ? v : 0.01f * v; }

__device__ __forceinline__ uint pack2(float a, float b) {
    union { uint u; ushort s[2]; } p;
    p.s[0] = __bfloat16_as_ushort(f2b(a));
    p.s[1] = __bfloat16_as_ushort(f2b(b));
    return p.u;
}
__device__ __forceinline__ void ld4(const bf16* p, float& v0, float& v1, float& v2, float& v3) {
    ushort4 r = *(const ushort4*)p;
    union { ushort u; bf16 b; } c0, c1, c2, c3;
    c0.u = r.x; c1.u = r.y; c2.u = r.z; c3.u = r.w;
    v0 = b2f(c0.b); v1 = b2f(c1.b); v2 = b2f(c2.b); v3 = b2f(c3.b);
}

// ---------------- Stage A: x1 = bn_lrelu(deconv(cv1, w0a, s1, pad(1,0,0))) ----
__global__ __launch_bounds__(256) void kA(const float* __restrict__ cv1,
                                          const float* __restrict__ w0a,
                                          const float* __restrict__ g0,
                                          const float* __restrict__ b0,
                                          bf16* __restrict__ x1) {
    __shared__ float lw[3][32][32];   // [u][ci][co] — broadcast reads
    __shared__ float lsc[32], lbi[32];
    const int tid = threadIdx.x;
    for (int i = tid; i < 32 * 32 * 3; i += 256) {
        int ci = i / 96, r = i - ci * 96, co = r / 3, u = r - co * 3;
        lw[u][ci][co] = w0a[i];
    }
    if (tid < 32) {
        lsc[tid] = g0[tid] * (1.0f / sqrtf(1.0f + 1e-5f));
        lbi[tid] = b0[tid];
    }
    __syncthreads();

    const int pos = blockIdx.x * 256 + tid;        // 196608 total
    const int x = pos & (cW0 - 1);
    const int y = (pos >> 7) & (cH0 - 1);
    const int z = pos >> 13;

    float acc[32];
    #pragma unroll
    for (int co = 0; co < 32; ++co) acc[co] = 0.f;

    #pragma unroll
    for (int u = 0; u < 3; ++u) {
        const int zi = z + 1 - u;
        if (zi < 0 || zi >= cD0) continue;
        const float* src = cv1 + (size_t)(zi * cH0 + y) * cW0 + x;
        for (int ci = 0; ci < 32; ++ci) {
            const float v = src[ci * PL0];
            const float4* wp = (const float4*)&lw[u][ci][0];
            #pragma unroll
            for (int q = 0; q < 8; ++q) {
                float4 wv = wp[q];
                acc[4*q+0] += v * wv.x; acc[4*q+1] += v * wv.y;
                acc[4*q+2] += v * wv.z; acc[4*q+3] += v * wv.w;
            }
        }
    }
    #pragma unroll
    for (int co = 0; co < 32; ++co)
        x1[co * PL0 + (size_t)(z * cH0 + y) * cW0 + x] =
            f2b(lrelu(acc[co] * lsc[co] + lbi[co]));
}

// ---------------- Stage B: x2 = bn_lrelu(deconv(x1, w0b, s2, pad(1,0,0))) ----
// One thread per INPUT position (od,ih,iw): computes the 2x2 (oh,ow) parity quad.
// Each 2B x1 load feeds 2kd*4quad*16co = 64 FMAs. Weight reads are wave-uniform
// LDS broadcasts. kw-pairs pack into one uint store (coalesced).
__global__ __launch_bounds__(256) void kB(const bf16* __restrict__ x1,
                                          const float* __restrict__ w0b,
                                          const float* __restrict__ g1,
                                          const float* __restrict__ b1,
                                          bf16* __restrict__ x2) {
    __shared__ float lw[4][32][4][16];   // [kd][ci][kh*2+kw][co]
    __shared__ float lsc[16], lbi[16];
    const int tid = threadIdx.x;
    for (int i = tid; i < 8192; i += 256) {
        // source layout (ci,co,kd,kh,kw): i = ci*256 + co*16 + kd*4 + kh*2 + kw
        int ci = i >> 8, co = (i >> 4) & 15, kd = (i >> 2) & 3, khkw = i & 3;
        lw[kd][ci][khkw][co] = w0b[i];
    }
    if (tid < 16) {
        lsc[tid] = g1[tid] * (1.0f / sqrtf(1.0f + 1e-5f));
        lbi[tid] = b1[tid];
    }
    __syncthreads();

    const int t  = blockIdx.x * 256 + tid;   // 393216 threads (1536 blocks)
    const int iw = t & 127;
    const int ih = (t >> 7) & 63;
    const int od = t >> 13;                  // 0..47
    const int p  = (od + 1) & 1;

    float acc[4][16];                        // [kh*2+kw][co]
    #pragma unroll
    for (int k = 0; k < 4; ++k)
        #pragma unroll
        for (int co = 0; co < 16; ++co) acc[k][co] = 0.f;

    #pragma unroll
    for (int j = 0; j < 2; ++j) {
        const int kd = p + 2 * j;
        const int id = (od + 1 - kd) >> 1;
        if (id < 0 || id >= cD0) continue;
        const bf16* src = x1 + (size_t)(id * cH0 + ih) * cW0 + iw;
        for (int ci = 0; ci < 32; ++ci) {
            const float v = b2f(src[ci * PL0]);
            #pragma unroll
            for (int k = 0; k < 4; ++k) {
                const float4* wp = (const float4*)&lw[kd][ci][k][0];
                #pragma unroll
                for (int q = 0; q < 4; ++q) {
                    float4 wv = wp[q];
                    acc[k][4*q+0] += v * wv.x; acc[k][4*q+1] += v * wv.y;
                    acc[k][4*q+2] += v * wv.z; acc[k][4*q+3] += v * wv.w;
                }
            }
        }
    }
    const int oh0 = 2 * ih, ow0 = 2 * iw;
    #pragma unroll
    for (int co = 0; co < 16; ++co) {
        const float sc = lsc[co], bi = lbi[co];
        #pragma unroll
        for (int kh = 0; kh < 2; ++kh) {
            uint pk = pack2(lrelu(acc[kh*2+0][co] * sc + bi),
                            lrelu(acc[kh*2+1][co] * sc + bi));
            *(uint*)(x2 + co * PL1 + (size_t)(od * cH1 + oh0 + kh) * cW1 + ow0) = pk;
        }
    }
}

// ---------------- Stage D: x3 = bn_lrelu(deconv(concat(x2,cv0), w1a, s1, pad(1,0,0)))
// Thread handles 4 consecutive x: ushort4 (x2) / float4 (cv0) loads, 64 FMAs per
// weight float4 (broadcast), packed uint2 bf16 stores.
__global__ __launch_bounds__(256) void kD(const bf16* __restrict__ x2,
                                          const float* __restrict__ cv0,
                                          const float* __restrict__ w1a,
                                          const float* __restrict__ g2,
                                          const float* __restrict__ b2v,
                                          bf16* __restrict__ x3) {
    __shared__ float lw[3][32][16];   // [u][ci][co] — broadcast reads
    __shared__ float lsc[16], lbi[16];
    const int tid = threadIdx.x;
    for (int i = tid; i < 1536; i += 256) {
        int ci = i / 48, r = i - ci * 48, co = r / 3, u = r - co * 3;
        lw[u][ci][co] = w1a[i];
    }
    if (tid < 16) {
        lsc[tid] = g2[tid] * (1.0f / sqrtf(1.0f + 1e-5f));
        lbi[tid] = b2v[tid];
    }
    __syncthreads();

    const int t  = blockIdx.x * 256 + tid;   // 393216 threads (1536 blocks)
    const int xq = t & 63;                   // x0 = 4*xq
    const int y  = (t >> 6) & 127;
    const int z  = t >> 13;                  // 0..47

    float acc[4][16];                        // [dx][co]
    #pragma unroll
    for (int k = 0; k < 4; ++k)
        #pragma unroll
        for (int co = 0; co < 16; ++co) acc[k][co] = 0.f;

    #pragma unroll
    for (int u = 0; u < 3; ++u) {
        const int zi = z + 1 - u;
        if (zi < 0 || zi >= cD1) continue;
        const size_t base = (size_t)(zi * cH1 + y) * cW1 + 4 * xq;
        for (int ci = 0; ci < 16; ++ci) {           // channels 0..15 = x2 (bf16)
            float v0, v1, v2, v3;
            ld4(x2 + ci * PL1 + base, v0, v1, v2, v3);
            const float4* wp = (const float4*)&lw[u][ci][0];
            #pragma unroll
            for (int q = 0; q < 4; ++q) {
                float4 wv = wp[q];
                acc[0][4*q+0] += v0 * wv.x; acc[0][4*q+1] += v0 * wv.y;
                acc[0][4*q+2] += v0 * wv.z; acc[0][4*q+3] += v0 * wv.w;
                acc[1][4*q+0] += v1 * wv.x; acc[1][4*q+1] += v1 * wv.y;
                acc[1][4*q+2] += v1 * wv.z; acc[1][4*q+3] += v1 * wv.w;
                acc[2][4*q+0] += v2 * wv.x; acc[2][4*q+1] += v2 * wv.y;
                acc[2][4*q+2] += v2 * wv.z; acc[2][4*q+3] += v2 * wv.w;
                acc[3][4*q+0] += v3 * wv.x; acc[3][4*q+1] += v3 * wv.y;
                acc[3][4*q+2] += v3 * wv.z; acc[3][4*q+3] += v3 * wv.w;
            }
        }
        for (int ci = 0; ci < 16; ++ci) {           // channels 16..31 = cv0 (f32)
            const float4 vv = *(const float4*)(cv0 + ci * PL1 + base);
            const float4* wp = (const float4*)&lw[u][16 + ci][0];
            #pragma unroll
            for (int q = 0; q < 4; ++q) {
                float4 wv = wp[q];
                acc[0][4*q+0] += vv.x * wv.x; acc[0][4*q+1] += vv.x * wv.y;
                acc[0][4*q+2] += vv.x * wv.z; acc[0][4*q+3] += vv.x * wv.w;
                acc[1][4*q+0] += vv.y * wv.x; acc[1][4*q+1] += vv.y * wv.y;
                acc[1][4*q+2] += vv.y * wv.z; acc[1][4*q+3] += vv.y * wv.w;
                acc[2][4*q+0] += vv.z * wv.x; acc[2][4*q+1] += vv.z * wv.y;
                acc[2][4*q+2] += vv.z * wv.z; acc[2][4*q+3] += vv.z * wv.w;
                acc[3][4*q+0] += vv.w * wv.x; acc[3][4*q+1] += vv.w * wv.y;
                acc[3][4*q+2] += vv.w * wv.z; acc[3][4*q+3] += vv.w * wv.w;
            }
        }
    }
    const size_t obase = (size_t)(z * cH1 + y) * cW1 + 4 * xq;
    #pragma unroll
    for (int co = 0; co < 16; ++co) {
        const float sc = lsc[co], bi = lbi[co];
        uint2 pk;
        pk.x = pack2(lrelu(acc[0][co] * sc + bi), lrelu(acc[1][co] * sc + bi));
        pk.y = pack2(lrelu(acc[2][co] * sc + bi), lrelu(acc[3][co] * sc + bi));
        *(uint2*)(x3 + co * PL1 + obase) = pk;
    }
}

// ---------------- Stage E: cost = bn_lrelu(deconv(x3, w1b, s2, pad(1,0,0))) ----
// Thread handles 4 consecutive iw for one (od,ih): ushort4 loads (16 FMAs each),
// emits the 2x2 parity quads as two 16B uint4 stores.
__global__ __launch_bounds__(256) void kE(const bf16* __restrict__ x3,
                                          const float* __restrict__ w1b,
                                          const float* __restrict__ g3,
                                          const float* __restrict__ b3v,
                                          bf16* __restrict__ cost) {
    __shared__ float lw[256];   // w1b (16,1,4,2,2): i = ci*16 + kd*4 + kh*2 + kw
    const int tid = threadIdx.x;
    lw[tid] = w1b[tid];
    __syncthreads();

    const int t  = blockIdx.x * 256 + tid;   // 786432 threads (3072 blocks)
    const int xq = t & 63;                   // iw0 = 4*xq
    const int ih = (t >> 6) & 127;
    const int od = t >> 13;                  // 0..95
    const int p  = (od + 1) & 1;

    float a[4][4];                           // [dx][kh*2+kw]
    #pragma unroll
    for (int dx = 0; dx < 4; ++dx)
        #pragma unroll
        for (int k = 0; k < 4; ++k) a[dx][k] = 0.f;

    #pragma unroll
    for (int j = 0; j < 2; ++j) {
        const int kd = p + 2 * j;
        const int id = (od + 1 - kd) >> 1;
        if (id < 0 || id >= cD1) continue;
        const size_t base = (size_t)(id * cH1 + ih) * cW1 + 4 * xq;
        #pragma unroll
        for (int ci = 0; ci < 16; ++ci) {
            float v0, v1, v2, v3;
            ld4(x3 + ci * PL1 + base, v0, v1, v2, v3);
            const float4 w = *(const float4*)&lw[ci * 16 + kd * 4];
            a[0][0] += v0 * w.x; a[0][1] += v0 * w.y; a[0][2] += v0 * w.z; a[0][3] += v0 * w.w;
            a[1][0] += v1 * w.x; a[1][1] += v1 * w.y; a[1][2] += v1 * w.z; a[1][3] += v1 * w.w;
            a[2][0] += v2 * w.x; a[2][1] += v2 * w.y; a[2][2] += v2 * w.z; a[2][3] += v2 * w.w;
            a[3][0] += v3 * w.x; a[3][1] += v3 * w.y; a[3][2] += v3 * w.z; a[3][3] += v3 * w.w;
        }
    }
    const float sc = g3[0] * (1.0f / sqrtf(1.0f + 1e-5f));
    const float bi = b3v[0];
    const int oh0 = 2 * ih;
    #pragma unroll
    for (int kh = 0; kh < 2; ++kh) {
        uint4 pk;
        pk.x = pack2(lrelu(a[0][kh*2+0] * sc + bi), lrelu(a[0][kh*2+1] * sc + bi));
        pk.y = pack2(lrelu(a[1][kh*2+0] * sc + bi), lrelu(a[1][kh*2+1] * sc + bi));
        pk.z = pack2(lrelu(a[2][kh*2+0] * sc + bi), lrelu(a[2][kh*2+1] * sc + bi));
        pk.w = pack2(lrelu(a[3][kh*2+0] * sc + bi), lrelu(a[3][kh*2+1] * sc + bi));
        *(uint4*)(cost + (size_t)(od * cH2 + oh0 + kh) * cW2 + 8 * xq) = pk;
    }
}

// ---------------- Stage F: 9-shift superpixel aggregation --------------------
// out[d,y,x] = Sum_{r,c} sp[r*3+c,y,x] * cost[d, y-4*(1-r), x-4*(1-c)], OOB -> 0
// Thread handles 4 consecutive x and 4 consecutive d. Shifts are multiples of 4,
// so OOB is uniform per x-quad; float4 sp loads, ushort4 cost loads, float4 stores.
__global__ __launch_bounds__(256) void kF(const bf16* __restrict__ cost,
                                          const float* __restrict__ sp,
                                          float* __restrict__ out) {
    const int t  = blockIdx.x * 256 + threadIdx.x;  // 786432 threads (3072 blocks)
    const int xq = t & 127;                  // x0 = 4*xq
    const int y  = (t >> 7) & 255;
    const int d0 = (t >> 15) * 4;            // 0..92
    const int x0 = 4 * xq;
    const size_t plane = (size_t)cH2 * cW2;

    float4 w4[9];
    int cyc[3], cxc[3];
    #pragma unroll
    for (int r = 0; r < 3; ++r) {
        const int cy = y - 4 * (1 - r);
        const bool vy = (cy >= 0) && (cy < cH2);
        cyc[r] = vy ? cy : y;
        #pragma unroll
        for (int c = 0; c < 3; ++c) {
            const int cx0 = x0 - 4 * (1 - c);
            const bool vx = (cx0 >= 0) && (cx0 <= cW2 - 4);
            if (r == 0) cxc[c] = vx ? cx0 : x0;
            if (vy && vx) {
                w4[r*3+c] = *(const float4*)(sp + (size_t)(r*3+c) * plane + (size_t)y * cW2 + x0);
            } else {
                w4[r*3+c] = make_float4(0.f, 0.f, 0.f, 0.f);
            }
        }
    }
    #pragma unroll
    for (int dd = 0; dd < 4; ++dd) {
        const int d = d0 + dd;
        const bf16* cp = cost + (size_t)d * plane;
        float a0 = 0.f, a1 = 0.f, a2 = 0.f, a3 = 0.f;
        #pragma unroll
        for (int r = 0; r < 3; ++r) {
            const size_t rb = (size_t)cyc[r] * cW2;
            #pragma unroll
            for (int c = 0; c < 3; ++c) {
                float v0, v1, v2, v3;
                ld4(cp + rb + cxc[c], v0, v1, v2, v3);
                const float4 w = w4[r*3+c];
                a0 += w.x * v0; a1 += w.y * v1; a2 += w.z * v2; a3 += w.w * v3;
            }
        }
        *(float4*)(out + (size_t)d * plane + (size_t)y * cW2 + x0) = make_float4(a0, a1, a2, a3);
    }
}

extern "C" void kernel_launch(void* const* d_in, const int* in_sizes, int n_in,
                              void* d_out, int out_size, void* d_ws, size_t ws_size,
                              hipStream_t stream) {
    const float* cv1 = (const float*)d_in[0];
    const float* cv0 = (const float*)d_in[1];
    const float* sp  = (const float*)d_in[2];
    const float* w0a = (const float*)d_in[3];
    const float* w0b = (const float*)d_in[4];
    const float* w1a = (const float*)d_in[5];
    const float* w1b = (const float*)d_in[6];
    const float* g0  = (const float*)d_in[7];
    const float* g1  = (const float*)d_in[8];
    const float* g2  = (const float*)d_in[9];
    const float* g3  = (const float*)d_in[10];
    const float* b0  = (const float*)d_in[11];
    const float* b1  = (const float*)d_in[12];
    const float* b2  = (const float*)d_in[13];
    const float* b3  = (const float*)d_in[14];

    // Workspace layout (bf16 intermediates, f32 accumulation inside kernels):
    //   x1  @ 0          : 12,582,912 B
    //   x2  @ 12,582,912 : 50,331,648 B   (ends 62,914,560)
    //   x3  @ 62,914,560 : 50,331,648 B   (ends 113,246,208)
    //   cost@ 0          : 25,165,824 B   (aliases dead x1 + part of dead x2)
    char* ws = (char*)d_ws;
    bf16* x1   = (bf16*)(ws);
    bf16* x2   = (bf16*)(ws + 12582912);
    bf16* x3   = (bf16*)(ws + 62914560);
    bf16* cost = (bf16*)(ws);

    kA<<<768,  256, 0, stream>>>(cv1, w0a, g0, b0, x1);
    kB<<<1536, 256, 0, stream>>>(x1, w0b, g1, b1, x2);
    kD<<<1536, 256, 0, stream>>>(x2, cv0, w1a, g2, b2, x3);
    kE<<<3072, 256, 0, stream>>>(x3, w1b, g3, b3, cost);
    kF<<<3072, 256, 0, stream>>>(cost, sp, (float*)d_out);
}